// Round 10
// baseline (220.527 us; speedup 1.0000x reference)
//
#include <hip/hip_runtime.h>

#define B_  2
#define S_  2048
#define D_  1024
#define H_  16
#define HD_ 64
#define MM  (B_ * S_)  // 4096 rows in all projection GEMMs

typedef __bf16 bf16;
typedef __attribute__((ext_vector_type(8))) __bf16 bf16x8;
typedef __attribute__((ext_vector_type(4))) __bf16 bf16x4;
typedef __attribute__((ext_vector_type(4))) float  f32x4;

// exp2 via the native v_exp_f32 (computes 2^x). Avoids glibc __exp2f macro.
__device__ inline float exp2g(float x) { return __builtin_amdgcn_exp2f(x); }

// Load 8 contiguous elements as bf16x8 (converting if fp32).
__device__ inline bf16x8 load8(const bf16* p) { return *(const bf16x8*)p; }
__device__ inline bf16x8 load8(const float* p) {
  float4 a = *(const float4*)p;
  float4 b = *(const float4*)(p + 4);
  bf16x8 r;
  r[0] = (bf16)a.x; r[1] = (bf16)a.y; r[2] = (bf16)a.z; r[3] = (bf16)a.w;
  r[4] = (bf16)b.x; r[5] = (bf16)b.y; r[6] = (bf16)b.z; r[7] = (bf16)b.w;
  return r;
}

// Barrier that publishes LDS writes but leaves register global-loads in
// flight (no vmcnt drain). ONLY valid in kernels with no cross-thread
// global-memory communication (pure global reads; outputs written after
// the loop). The compiler still inserts counted vmcnt waits before any
// ds_write of a loaded register (RAW on the reg) — the wait we want.
__device__ inline void barrier_lds() {
  asm volatile("s_waitcnt lgkmcnt(0)" ::: "memory");
  __builtin_amdgcn_s_barrier();
}

// ---------------------------------------------------------------------------
// z 0..3: 32x32-tiled weight transpose fp32->bf16.
// z 4..15: bulk fp32->bf16 convert of q_in/k_in/v_in (1M elems per plane).
// ---------------------------------------------------------------------------
__global__ __launch_bounds__(256) void transpose_w(
    const float* __restrict__ W0, const float* __restrict__ W1,
    const float* __restrict__ W2, const float* __restrict__ W3,
    bf16* __restrict__ T0, bf16* __restrict__ T1,
    bf16* __restrict__ T2, bf16* __restrict__ T3,
    const float* __restrict__ X0, const float* __restrict__ X1,
    const float* __restrict__ X2,
    bf16* __restrict__ Y0, bf16* __restrict__ Y1, bf16* __restrict__ Y2) {
  const int z = blockIdx.z;
  if (z >= 4) {  // convert plane
    const int p = z - 4, t = p >> 2;
    const float* src = t == 0 ? X0 : t == 1 ? X1 : X2;
    bf16* dst = t == 0 ? Y0 : t == 1 ? Y1 : Y2;
    long base = ((long)(p & 3) << 20) +
                (long)(blockIdx.y * 32 + blockIdx.x) * 1024 + threadIdx.x * 4;
    float4 v = *(const float4*)&src[base];
    bf16x4 o4;
    o4[0] = (bf16)v.x; o4[1] = (bf16)v.y; o4[2] = (bf16)v.z; o4[3] = (bf16)v.w;
    *(bf16x4*)&dst[base] = o4;
    return;
  }
  __shared__ bf16 t[32][40];
  const float* in = z == 0 ? W0 : z == 1 ? W1 : z == 2 ? W2 : W3;
  bf16* out = z == 0 ? T0 : z == 1 ? T1 : z == 2 ? T2 : T3;
  const int tx = threadIdx.x & 31;
  const int ty = threadIdx.x >> 5;  // 0..7
  const int r0 = blockIdx.y * 32, c0 = blockIdx.x * 32;
#pragma unroll
  for (int j = 0; j < 32; j += 8)
    t[ty + j][tx] = (bf16)in[(long)(r0 + ty + j) * D_ + (c0 + tx)];
  __syncthreads();
#pragma unroll
  for (int j = 0; j < 32; j += 8)
    out[(long)(c0 + ty + j) * D_ + (r0 + tx)] = t[tx][ty + j];
}

// ---------------------------------------------------------------------------
// V [B,S,H,HD] (bf16) -> VT [B,H,HD,S]  (coalesced LDS-bounce transpose)
// ---------------------------------------------------------------------------
__global__ __launch_bounds__(256) void transpose_v64(const bf16* __restrict__ V,
                                                     bf16* __restrict__ VT) {
  __shared__ bf16 t[64][72];
  const int tid = threadIdx.x;
  const int s0 = blockIdx.x * 64;
  const int bh = blockIdx.y;
  const int b = bh >> 4, h = bh & 15;
  const bf16* ip = V + (long)b * S_ * D_ + h * HD_;
  bf16* op = VT + (long)bh * HD_ * S_;
#pragma unroll
  for (int i = 0; i < 2; ++i) {
    int c = tid + i * 256;
    int r = c >> 3, cc = (c & 7) * 8;
    *(bf16x8*)&t[r][cc] = *(const bf16x8*)&ip[(long)(s0 + r) * D_ + cc];
  }
  __syncthreads();
#pragma unroll
  for (int i = 0; i < 2; ++i) {
    int c = tid + i * 256;
    int d = c >> 3, sc = (c & 7) * 8;
    bf16x8 v;
#pragma unroll
    for (int j = 0; j < 8; ++j) v[j] = t[sc + j][d];
    *(bf16x8*)&op[(long)d * S_ + s0 + sc] = v;
  }
}

// ---------------------------------------------------------------------------
// Batched C[M,N] = A[M,K] @ Bt[N,K]^T + bias[N], z selects operand triple.
// R22 (flash-v8 recipe ported): REGISTER staging at prefetch distance 2 +
// lgkmcnt-only barriers. While computing tile t the loads for t+2 are being
// issued; the regs committed to LDS at step t were issued a full iteration
// + barrier earlier (vmcnt wait ~0). No global_load_lds => __syncthreads'
// vmcnt(0) drain is unnecessary; barrier_lds() publishes ds_writes only.
// Differs from R4's failed counted-ring: waits are per-wave counted vmcnt
// on register RAW (compiler-inserted), not block-wide ledger asm.
// 128x128 tiles, BK=32, 2 LDS buffers (32 KB). R16 XCD swizzle kept.
// ---------------------------------------------------------------------------
template <typename AT, typename OT>
__global__ __launch_bounds__(256) void gemm_bt_dma(
    const AT* __restrict__ A0, const AT* __restrict__ A1, const AT* __restrict__ A2,
    const bf16* __restrict__ B0, const bf16* __restrict__ B1, const bf16* __restrict__ B2,
    const float* __restrict__ c0, const float* __restrict__ c1, const float* __restrict__ c2,
    OT* __restrict__ C0, OT* __restrict__ C1, OT* __restrict__ C2,
    int M, int N, int K) {
  __shared__ bf16 lA[2][128][32];  // [dbuf][row][k]
  __shared__ bf16 lB[2][128][32];
  const int z = blockIdx.z;
  const AT*    A    = z == 0 ? A0 : z == 1 ? A1 : A2;
  const bf16*  Bt   = z == 0 ? B0 : z == 1 ? B1 : B2;
  const float* bias = z == 0 ? c0 : z == 1 ? c1 : c2;
  OT*          C    = z == 0 ? C0 : z == 1 ? C1 : C2;

  const int tid = threadIdx.x;
  const int lane = tid & 63, wave = tid >> 6;
  const int quad = lane >> 4, l16 = lane & 15;
  // bijective XCD swizzle within the 256-block z-plane (256 % 8 == 0)
  const int id = blockIdx.x + (blockIdx.y << 3);
  const int nid = (id & 7) * 32 + (id >> 3);
  const int bm = (nid >> 3) * 128, bn = (nid & 7) * 128;
  const int wm = (wave >> 1) * 64, wn = (wave & 1) * 64;

  f32x4 acc[4][4] = {};
  const int NT = K >> 5;  // 32-wide K steps; K=1024 -> 32 (even)

  const int srow = tid >> 2, skc = (tid & 3) * 8;  // staging chunk mapping

  // load one 32-wide K step into a named register set (2 chunks per operand)
#define LOADSET(ra0, ra1, rb0, rb1, t)                                       \
  {                                                                          \
    const int k0 = (t) << 5;                                                 \
    ra0 = load8(&A[(long)(bm + srow) * K + k0 + skc]);                       \
    ra1 = load8(&A[(long)(bm + srow + 64) * K + k0 + skc]);                  \
    rb0 = load8(&Bt[(long)(bn + srow) * K + k0 + skc]);                      \
    rb1 = load8(&Bt[(long)(bn + srow + 64) * K + k0 + skc]);                 \
  }
#define WRITESET(buf, ra0, ra1, rb0, rb1)                                    \
  {                                                                          \
    *(bf16x8*)&lA[buf][srow][skc] = ra0;                                     \
    *(bf16x8*)&lA[buf][srow + 64][skc] = ra1;                                \
    *(bf16x8*)&lB[buf][srow][skc] = rb0;                                     \
    *(bf16x8*)&lB[buf][srow + 64][skc] = rb1;                                \
  }
#define COMPUTE(buf)                                                         \
  {                                                                          \
    bf16x8 af[4], bfr[4];                                                    \
    _Pragma("unroll") for (int i = 0; i < 4; ++i) {                          \
      af[i]  = *(const bf16x8*)&lA[buf][wm + i * 16 + l16][quad * 8];        \
      bfr[i] = *(const bf16x8*)&lB[buf][wn + i * 16 + l16][quad * 8];        \
    }                                                                        \
    _Pragma("unroll") for (int mi = 0; mi < 4; ++mi)                         \
      _Pragma("unroll") for (int ni = 0; ni < 4; ++ni)                       \
        acc[mi][ni] = __builtin_amdgcn_mfma_f32_16x16x32_bf16(               \
            af[mi], bfr[ni], acc[mi][ni], 0, 0, 0);                          \
  }

  bf16x8 a0, a1, b0, b1;  // set S0
  bf16x8 a2, a3, b2, b3;  // set S1

  // prologue: tile 0 -> LDS[0]; tile 1 issued into S0 (in flight)
  LOADSET(a0, a1, b0, b1, 0);
  WRITESET(0, a0, a1, b0, b1);
  LOADSET(a0, a1, b0, b1, 1);
  barrier_lds();

  for (int kt = 0; kt < NT; kt += 2) {
    // even: issue tile kt+2 -> S1; compute buf0 (tile kt); commit S0 -> buf1
    if (kt + 2 < NT) LOADSET(a2, a3, b2, b3, kt + 2);
    COMPUTE(0);
    WRITESET(1, a0, a1, b0, b1);
    barrier_lds();
    // odd: issue tile kt+3 -> S0; compute buf1 (tile kt+1); commit S1 -> buf0
    if (kt + 3 < NT) LOADSET(a0, a1, b0, b1, kt + 3);
    COMPUTE(1);
    if (kt + 2 < NT) {
      WRITESET(0, a2, a3, b2, b3);
      barrier_lds();
    }
  }
#undef LOADSET
#undef WRITESET
#undef COMPUTE

  // epilogue: C/D layout col=lane&15, row=quad*4+reg (m89-verified)
#pragma unroll
  for (int mi = 0; mi < 4; ++mi)
#pragma unroll
    for (int ni = 0; ni < 4; ++ni) {
      int col = bn + wn + ni * 16 + l16;
      float bv = bias[col];
#pragma unroll
      for (int r = 0; r < 4; ++r) {
        int row = bm + wm + mi * 16 + quad * 4 + r;
        C[(long)row * N + col] = (OT)(acc[mi][ni][r] + bv);
      }
    }
}

// ---------------------------------------------------------------------------
// Final GEMM: 128x64 tiles (512 blocks). R22: same reg-staged distance-2
// prefetch + lgkmcnt-only barriers. R16 XCD swizzle kept.
// ---------------------------------------------------------------------------
__global__ __launch_bounds__(256) void gemm_bt_64(const bf16* __restrict__ A,
                                                  const bf16* __restrict__ Bt,
                                                  const float* __restrict__ bias,
                                                  float* __restrict__ C,
                                                  int M, int N, int K) {
  __shared__ bf16 lA[2][128][32];
  __shared__ bf16 lB[2][64][32];
  const int tid = threadIdx.x;
  const int lane = tid & 63, wave = tid >> 6;
  const int quad = lane >> 4, l16 = lane & 15;
  const int id = blockIdx.x + (blockIdx.y << 4);
  const int nid = (id & 7) * 64 + (id >> 3);
  const int bm = (nid >> 4) * 128, bn = (nid & 15) * 64;
  const int wm = (wave >> 1) * 64, wn = (wave & 1) * 32;

  f32x4 acc[4][2] = {};
  const int NT = K >> 5;  // even

  const int srow = tid >> 2, skc = (tid & 3) * 8;

#define LOADSET64(ra0, ra1, rb0, t)                                          \
  {                                                                          \
    const int k0 = (t) << 5;                                                 \
    ra0 = load8(&A[(long)(bm + srow) * K + k0 + skc]);                       \
    ra1 = load8(&A[(long)(bm + srow + 64) * K + k0 + skc]);                  \
    rb0 = load8(&Bt[(long)(bn + srow) * K + k0 + skc]);                      \
  }
#define WRITESET64(buf, ra0, ra1, rb0)                                       \
  {                                                                          \
    *(bf16x8*)&lA[buf][srow][skc] = ra0;                                     \
    *(bf16x8*)&lA[buf][srow + 64][skc] = ra1;                                \
    *(bf16x8*)&lB[buf][srow][skc] = rb0;                                     \
  }
#define COMPUTE64(buf)                                                       \
  {                                                                          \
    bf16x8 af[4], bfr[2];                                                    \
    _Pragma("unroll") for (int i = 0; i < 4; ++i)                            \
      af[i] = *(const bf16x8*)&lA[buf][wm + i * 16 + l16][quad * 8];         \
    _Pragma("unroll") for (int i = 0; i < 2; ++i)                            \
      bfr[i] = *(const bf16x8*)&lB[buf][wn + i * 16 + l16][quad * 8];        \
    _Pragma("unroll") for (int mi = 0; mi < 4; ++mi)                         \
      _Pragma("unroll") for (int ni = 0; ni < 2; ++ni)                       \
        acc[mi][ni] = __builtin_amdgcn_mfma_f32_16x16x32_bf16(               \
            af[mi], bfr[ni], acc[mi][ni], 0, 0, 0);                          \
  }

  bf16x8 a0, a1, b0;  // set S0
  bf16x8 a2, a3, b2;  // set S1

  LOADSET64(a0, a1, b0, 0);
  WRITESET64(0, a0, a1, b0);
  LOADSET64(a0, a1, b0, 1);
  barrier_lds();

  for (int kt = 0; kt < NT; kt += 2) {
    if (kt + 2 < NT) LOADSET64(a2, a3, b2, kt + 2);
    COMPUTE64(0);
    WRITESET64(1, a0, a1, b0);
    barrier_lds();
    if (kt + 3 < NT) LOADSET64(a0, a1, b0, kt + 3);
    COMPUTE64(1);
    if (kt + 2 < NT) {
      WRITESET64(0, a2, a3, b2);
      barrier_lds();
    }
  }
#undef LOADSET64
#undef WRITESET64
#undef COMPUTE64

#pragma unroll
  for (int mi = 0; mi < 4; ++mi)
#pragma unroll
    for (int ni = 0; ni < 2; ++ni) {
      int col = bn + wn + ni * 16 + l16;
      float bv = bias[col];
#pragma unroll
      for (int r = 0; r < 4; ++r) {
        int row = bm + wm + mi * 16 + quad * 4 + r;
        C[(long)row * N + col] = acc[mi][ni][r] + bv;
      }
    }
}

// ---------------------------------------------------------------------------
// Flash attention v9 = v8 + lgkmcnt-only barriers + setprio(T5).  (R8: both
// heavy kernels now below the fill-dispatch cutoff; kept frozen.)
// ---------------------------------------------------------------------------
#define SCALE_LOG2E 0.1803368801111244f  // (1/8) * log2(e)

__device__ inline void attn_step5(bool diag, int qloc, int quad, int l16,
                                  const bf16 (*lKb)[64], const bf16 (*lVb)[64],
                                  bf16 (*lpw)[72], const bf16x8* aq,
                                  f32x4* o, float& l_s) {
  const int sw = l16 & 7;
  f32x4 s[4];
  __builtin_amdgcn_s_setprio(1);
#pragma unroll
  for (int ni = 0; ni < 4; ++ni) {
    f32x4 a = {};
#pragma unroll
    for (int c = 0; c < 2; ++c) {
      bf16x8 kf = *(const bf16x8*)&lKb[ni * 16 + l16][((c * 4 + quad) ^ sw) * 8];
      a = __builtin_amdgcn_mfma_f32_16x16x32_bf16(kf, aq[c], a, 0, 0, 0);
    }
    s[ni] = a * SCALE_LOG2E;
  }
  __builtin_amdgcn_s_setprio(0);
  if (diag) {
#pragma unroll
    for (int ni = 0; ni < 4; ++ni)
#pragma unroll
      for (int r = 0; r < 4; ++r)
        if (ni * 16 + quad * 4 + r > qloc) s[ni][r] = -1e9f;  // exp2 -> 0
  }
  float rs = 0.f;
#pragma unroll
  for (int ni = 0; ni < 4; ++ni) {
    bf16x4 p4;
#pragma unroll
    for (int r = 0; r < 4; ++r) {
      float p = exp2g(s[ni][r]);
      p4[r] = (bf16)p;
      rs += p;
    }
    *(bf16x4*)&lpw[l16][ni * 16 + quad * 4] = p4;  // P[q][key], packed b64
  }
  l_s += rs;
  __builtin_amdgcn_s_setprio(1);
#pragma unroll
  for (int c = 0; c < 2; ++c) {
    bf16x8 ap = *(const bf16x8*)&lpw[l16][c * 32 + quad * 8];
#pragma unroll
    for (int di = 0; di < 4; ++di) {
      bf16x8 vf = *(const bf16x8*)&lVb[di * 16 + l16][((c * 4 + quad) ^ sw) * 8];
      o[di] = __builtin_amdgcn_mfma_f32_16x16x32_bf16(vf, ap, o[di], 0, 0, 0);
    }
  }
  __builtin_amdgcn_s_setprio(0);
}

__device__ inline void store_o(bf16* Ob, int qrow, int lane, int quad, int l16,
                               bf16 (*lpw)[72], const f32x4* o, float l_s) {
  float rs = l_s;
  rs += __shfl_xor(rs, 16);
  rs += __shfl_xor(rs, 32);
  const float inv = 1.0f / rs;
#pragma unroll
  for (int di = 0; di < 4; ++di) {
    bf16x4 p4;
#pragma unroll
    for (int r = 0; r < 4; ++r) p4[r] = (bf16)(o[di][r] * inv);
    *(bf16x4*)&lpw[l16][di * 16 + quad * 4] = p4;
  }
  const int q = lane >> 2, db = (lane & 3) * 16;
  bf16x8 v0 = *(const bf16x8*)&lpw[q][db];
  bf16x8 v1 = *(const bf16x8*)&lpw[q][db + 8];
  *(bf16x8*)&Ob[(long)(qrow + q) * D_ + db] = v0;
  *(bf16x8*)&Ob[(long)(qrow + q) * D_ + db + 8] = v1;
}

__global__ __launch_bounds__(512) void flash_attn9(const bf16* __restrict__ Q,
                                                   const bf16* __restrict__ K,
                                                   const bf16* __restrict__ VT,
                                                   bf16* __restrict__ O) {
  __shared__ bf16 lK[2][64][64];   // [key][dim], chunk-col XOR-swizzled
  __shared__ bf16 lV[2][64][64];   // [dim][key], chunk-col XOR-swizzled
  __shared__ bf16 lp[8][16][72];   // per-wave P / O bounce
  const int tid = threadIdx.x;
  const int lane = tid & 63, wave = tid >> 6;  // 0..7
  const int quad = lane >> 4, l16 = lane & 15;
  const int x = blockIdx.x, bh = blockIdx.y;
  // adjacent pairing; reversed in the upper bh half for per-CU load balance
  const bool flip = (bh & 16) != 0;
  const int qtA = flip ? 30 - 2 * x : 2 * x;
  const int qtB = qtA + 1;
  const bool isB = wave >= 4;
  const int w4 = wave & 3;
  const int myqt = isB ? qtB : qtA;
  const int b = bh >> 4, h = bh & 15;
  const bf16* Qb = Q + (long)b * S_ * D_ + h * HD_;
  const bf16* Kb = K + (long)b * S_ * D_ + h * HD_;
  const bf16* Vb = VT + (long)bh * HD_ * S_;
  const int qrow = myqt * 64 + w4 * 16;
  const int qloc = w4 * 16 + l16;

  bf16x8 aq[2];
#pragma unroll
  for (int c = 0; c < 2; ++c)
    aq[c] = *(const bf16x8*)&Qb[(long)(qrow + l16) * D_ + c * 32 + quad * 8];

  f32x4 o[4] = {};
  float l_s = 0.f;

  const int srow = tid >> 3, scol = tid & 7;
  const int swcol = (scol ^ (srow & 7)) * 8;
  const int ktMax = qtB;  // always odd

  // prologue: stage tile 0 into buf0; issue tile 1 (in flight across barrier)
  bf16x8 rkA, rvA, rkB, rvB;
  rkA = *(const bf16x8*)&Kb[(long)srow * D_ + scol * 8];
  rvA = *(const bf16x8*)&Vb[(long)srow * S_ + scol * 8];
  *(bf16x8*)&lK[0][srow][swcol] = rkA;
  *(bf16x8*)&lV[0][srow][swcol] = rvA;
  rkA = *(const bf16x8*)&Kb[(long)(64 + srow) * D_ + scol * 8];
  rvA = *(const bf16x8*)&Vb[(long)srow * S_ + 64 + scol * 8];
  barrier_lds();  // publish LDS; keep tile-1 loads in flight

  for (int kt = 0; kt < ktMax; kt += 2) {
    // ---- even step: compute tile kt on buf0; commit rA (tile kt+1) -> buf1
    if (kt + 2 <= ktMax) {  // issue tile kt+2 -> rB (consumed next even step)
      const long k0 = (long)(kt + 2) * 64;
      rkB = *(const bf16x8*)&Kb[(k0 + srow) * D_ + scol * 8];
      rvB = *(const bf16x8*)&Vb[(long)srow * S_ + k0 + scol * 8];
    }
    if (isB || kt <= qtA)
      attn_step5(kt == myqt, qloc, quad, l16, lK[0], lV[0], lp[wave], aq,
                 o, l_s);
    *(bf16x8*)&lK[1][srow][swcol] = rkA;  // compiler waits vmcnt for rA only
    *(bf16x8*)&lV[1][srow][swcol] = rvA;
    barrier_lds();  // rB loads stay in flight across the barrier
    // ---- odd step: compute tile kt+1 on buf1; commit rB (tile kt+2) -> buf0
    if (kt + 3 <= ktMax) {  // issue tile kt+3 -> rA
      const long k0 = (long)(kt + 3) * 64;
      rkA = *(const bf16x8*)&Kb[(k0 + srow) * D_ + scol * 8];
      rvA = *(const bf16x8*)&Vb[(long)srow * S_ + k0 + scol * 8];
    }
    if (isB || kt + 1 <= qtA)
      attn_step5(kt + 1 == myqt, qloc, quad, l16, lK[1], lV[1], lp[wave], aq,
                 o, l_s);
    if (kt + 1 < ktMax) {
      *(bf16x8*)&lK[0][srow][swcol] = rkB;
      *(bf16x8*)&lV[0][srow][swcol] = rvB;
      barrier_lds();
    }
  }

  bf16* Ob = O + (long)b * S_ * D_ + h * HD_;
  store_o(Ob, qrow, lane, quad, l16, lp[wave], o, l_s);
}

// ---------------------------------------------------------------------------
extern "C" void kernel_launch(void* const* d_in, const int* in_sizes, int n_in,
                              void* d_out, int out_size, void* d_ws, size_t ws_size,
                              hipStream_t stream) {
  (void)in_sizes; (void)n_in; (void)out_size;
  const float* q_in = (const float*)d_in[0];
  const float* k_in = (const float*)d_in[1];
  const float* v_in = (const float*)d_in[2];
  const float* Wq   = (const float*)d_in[3];
  const float* bq   = (const float*)d_in[4];
  const float* Wk   = (const float*)d_in[5];
  const float* bk   = (const float*)d_in[6];
  const float* Wv   = (const float*)d_in[7];
  const float* bv   = (const float*)d_in[8];
  const float* Wo   = (const float*)d_in[9];
  const float* bo   = (const float*)d_in[10];
  float* out = (float*)d_out;  // reference output dtype is float32

  bf16* ws = (bf16*)d_ws;
  const size_t WSZ = (size_t)D_ * D_;       // 1M elements
  const size_t TSZ = (size_t)B_ * S_ * D_;  // 4M elements
  bf16* WqT = ws;
  bf16* WkT = WqT + WSZ;
  bf16* WvT = WkT + WSZ;
  bf16* WoT = WvT + WSZ;
  bf16* Qp  = WoT + WSZ;
  bf16* Kp  = Qp + TSZ;
  bf16* Vp  = Kp + TSZ;
  bf16* VTp = Vp + TSZ;
  bf16* Ap  = VTp + TSZ;   // 48 MB used through here (validated R2-R14)
  // converted inputs: lifetimes end before VTp/Ap are written -> overlap
  bf16* Xq  = VTp;
  bf16* Xk  = Ap;
  bf16* Xv  = Ap + TSZ;    // needs ws_size >= 56 MB (validated R8-R14)
  const bool pre = ws_size >= (4 * WSZ + 6 * TSZ) * sizeof(bf16);

  dim3 blk(256);
  transpose_w<<<dim3(32, 32, pre ? 16 : 4), blk, 0, stream>>>(
      Wq, Wk, Wv, Wo, WqT, WkT, WvT, WoT, q_in, k_in, v_in, Xq, Xk, Xv);

  if (pre)
    gemm_bt_dma<bf16, bf16><<<dim3(8, 32, 3), blk, 0, stream>>>(
        Xq, Xk, Xv, WqT, WkT, WvT, bq, bk, bv, Qp, Kp, Vp, MM, D_, D_);
  else
    gemm_bt_dma<float, bf16><<<dim3(8, 32, 3), blk, 0, stream>>>(
        q_in, k_in, v_in, WqT, WkT, WvT, bq, bk, bv, Qp, Kp, Vp, MM, D_, D_);

  transpose_v64<<<dim3(S_ / 64, B_ * H_), blk, 0, stream>>>(Vp, VTp);

  flash_attn9<<<dim3(16, B_ * H_), dim3(512), 0, stream>>>(Qp, Kp, VTp, Ap);

  gemm_bt_64<<<dim3(16, 32), blk, 0, stream>>>(Ap, WoT, bo, out, MM, D_, D_);
}

// Round 11
// 211.071 us; speedup vs baseline: 1.0448x; 1.0448x over previous
//
#include <hip/hip_runtime.h>

#define B_  2
#define S_  2048
#define D_  1024
#define H_  16
#define HD_ 64
#define MM  (B_ * S_)  // 4096 rows in all projection GEMMs

typedef __bf16 bf16;
typedef __attribute__((ext_vector_type(8))) __bf16 bf16x8;
typedef __attribute__((ext_vector_type(4))) __bf16 bf16x4;
typedef __attribute__((ext_vector_type(4))) float  f32x4;

// exp2 via the native v_exp_f32 (computes 2^x). Avoids glibc __exp2f macro.
__device__ inline float exp2g(float x) { return __builtin_amdgcn_exp2f(x); }

// Load 8 contiguous elements as bf16x8 (converting if fp32).
__device__ inline bf16x8 load8(const bf16* p) { return *(const bf16x8*)p; }
__device__ inline bf16x8 load8(const float* p) {
  float4 a = *(const float4*)p;
  float4 b = *(const float4*)(p + 4);
  bf16x8 r;
  r[0] = (bf16)a.x; r[1] = (bf16)a.y; r[2] = (bf16)a.z; r[3] = (bf16)a.w;
  r[4] = (bf16)b.x; r[5] = (bf16)b.y; r[6] = (bf16)b.z; r[7] = (bf16)b.w;
  return r;
}

// Async global->LDS DMA, 16 B per lane (dest = wave-uniform base + lane*16).
__device__ inline void gld16(void* lds, const void* g) {
  __builtin_amdgcn_global_load_lds(
      (const __attribute__((address_space(1))) unsigned int*)g,
      (__attribute__((address_space(3))) unsigned int*)lds, 16, 0, 0);
}

// Barrier that publishes LDS writes but leaves register global-loads in
// flight (no vmcnt drain). ONLY valid in kernels with no cross-thread
// global-memory communication (flash: global reads; O written post-loop).
// The compiler still inserts counted vmcnt waits before each ds_write of a
// loaded register (RAW on the reg) — exactly the wait we want.
__device__ inline void barrier_lds() {
  asm volatile("s_waitcnt lgkmcnt(0)" ::: "memory");
  __builtin_amdgcn_s_barrier();
}

// ---------------------------------------------------------------------------
// z 0..3: 32x32-tiled weight transpose fp32->bf16.
// z 4..15: bulk fp32->bf16 convert of q_in/k_in/v_in (1M elems per plane).
// ---------------------------------------------------------------------------
__global__ __launch_bounds__(256) void transpose_w(
    const float* __restrict__ W0, const float* __restrict__ W1,
    const float* __restrict__ W2, const float* __restrict__ W3,
    bf16* __restrict__ T0, bf16* __restrict__ T1,
    bf16* __restrict__ T2, bf16* __restrict__ T3,
    const float* __restrict__ X0, const float* __restrict__ X1,
    const float* __restrict__ X2,
    bf16* __restrict__ Y0, bf16* __restrict__ Y1, bf16* __restrict__ Y2) {
  const int z = blockIdx.z;
  if (z >= 4) {  // convert plane
    const int p = z - 4, t = p >> 2;
    const float* src = t == 0 ? X0 : t == 1 ? X1 : X2;
    bf16* dst = t == 0 ? Y0 : t == 1 ? Y1 : Y2;
    long base = ((long)(p & 3) << 20) +
                (long)(blockIdx.y * 32 + blockIdx.x) * 1024 + threadIdx.x * 4;
    float4 v = *(const float4*)&src[base];
    bf16x4 o4;
    o4[0] = (bf16)v.x; o4[1] = (bf16)v.y; o4[2] = (bf16)v.z; o4[3] = (bf16)v.w;
    *(bf16x4*)&dst[base] = o4;
    return;
  }
  __shared__ bf16 t[32][40];
  const float* in = z == 0 ? W0 : z == 1 ? W1 : z == 2 ? W2 : W3;
  bf16* out = z == 0 ? T0 : z == 1 ? T1 : z == 2 ? T2 : T3;
  const int tx = threadIdx.x & 31;
  const int ty = threadIdx.x >> 5;  // 0..7
  const int r0 = blockIdx.y * 32, c0 = blockIdx.x * 32;
#pragma unroll
  for (int j = 0; j < 32; j += 8)
    t[ty + j][tx] = (bf16)in[(long)(r0 + ty + j) * D_ + (c0 + tx)];
  __syncthreads();
#pragma unroll
  for (int j = 0; j < 32; j += 8)
    out[(long)(c0 + ty + j) * D_ + (r0 + tx)] = t[tx][ty + j];
}

// ---------------------------------------------------------------------------
// V [B,S,H,HD] (bf16) -> VT [B,H,HD,S]  (coalesced LDS-bounce transpose)
// ---------------------------------------------------------------------------
__global__ __launch_bounds__(256) void transpose_v64(const bf16* __restrict__ V,
                                                     bf16* __restrict__ VT) {
  __shared__ bf16 t[64][72];
  const int tid = threadIdx.x;
  const int s0 = blockIdx.x * 64;
  const int bh = blockIdx.y;
  const int b = bh >> 4, h = bh & 15;
  const bf16* ip = V + (long)b * S_ * D_ + h * HD_;
  bf16* op = VT + (long)bh * HD_ * S_;
#pragma unroll
  for (int i = 0; i < 2; ++i) {
    int c = tid + i * 256;
    int r = c >> 3, cc = (c & 7) * 8;
    *(bf16x8*)&t[r][cc] = *(const bf16x8*)&ip[(long)(s0 + r) * D_ + cc];
  }
  __syncthreads();
#pragma unroll
  for (int i = 0; i < 2; ++i) {
    int c = tid + i * 256;
    int d = c >> 3, sc = (c & 7) * 8;
    bf16x8 v;
#pragma unroll
    for (int j = 0; j < 8; ++j) v[j] = t[sc + j][d];
    *(bf16x8*)&op[(long)d * S_ + s0 + sc] = v;
  }
}

// ---------------------------------------------------------------------------
// Batched C[M,N] = A[M,K] @ Bt[N,K]^T + bias[N], z selects operand triple.
// R24: locked to the session-best structure (R3, measured 41.0 us):
// 128x128 tiles, BK=32 double-buffered 2-phase gld16 staging, drain-0
// __syncthreads (required: global_load_lds must land before readers pass).
// Measured & rejected alternatives: counted 3-ring 43.7, fused V-transpose
// epilogue 49.7, 128x64 tiles 56.2, reg-staged distance-2 51.1.
// R16 XCD swizzle kept (each XCD: 4 bm-panels x all bn, L2-resident).
// ---------------------------------------------------------------------------
template <typename AT, typename OT>
__global__ __launch_bounds__(256) void gemm_bt_dma(
    const AT* __restrict__ A0, const AT* __restrict__ A1, const AT* __restrict__ A2,
    const bf16* __restrict__ B0, const bf16* __restrict__ B1, const bf16* __restrict__ B2,
    const float* __restrict__ c0, const float* __restrict__ c1, const float* __restrict__ c2,
    OT* __restrict__ C0, OT* __restrict__ C1, OT* __restrict__ C2,
    int M, int N, int K) {
  __shared__ bf16 lA[2][128][32];  // [dbuf][row][k]
  __shared__ bf16 lB[2][128][32];
  const int z = blockIdx.z;
  const AT*    A    = z == 0 ? A0 : z == 1 ? A1 : A2;
  const bf16*  Bt   = z == 0 ? B0 : z == 1 ? B1 : B2;
  const float* bias = z == 0 ? c0 : z == 1 ? c1 : c2;
  OT*          C    = z == 0 ? C0 : z == 1 ? C1 : C2;

  const int tid = threadIdx.x;
  const int lane = tid & 63, wave = tid >> 6;
  const int quad = lane >> 4, l16 = lane & 15;
  // bijective XCD swizzle within the 256-block z-plane (256 % 8 == 0)
  const int id = blockIdx.x + (blockIdx.y << 3);
  const int nid = (id & 7) * 32 + (id >> 3);
  const int bm = (nid >> 3) * 128, bn = (nid & 7) * 128;
  const int wm = (wave >> 1) * 64, wn = (wave & 1) * 64;

  f32x4 acc[4][4] = {};
  const int NT = K >> 5;  // 32-wide K steps

  // ---- stage step t (K cols [t*32, t*32+32)) into buffer buf
#define STAGE_DMA(buf, t)                                                    \
  {                                                                          \
    const int k0 = (t) << 5;                                                 \
    _Pragma("unroll") for (int i = 0; i < 2; ++i) {                          \
      const int nbase = wave * 128 + i * 64; /* wave-uniform chunk base */   \
      const int n = nbase + lane;                                            \
      const int row = n >> 2, kc = (n & 3) * 8;                              \
      gld16(&lB[buf][0][0] + (long)nbase * 8,                                \
            &Bt[(long)(bn + row) * K + k0 + kc]);                            \
      if constexpr (__is_same(AT, bf16))                                     \
        gld16(&lA[buf][0][0] + (long)nbase * 8,                              \
              &A[(long)(bm + row) * K + k0 + kc]);                           \
    }                                                                        \
    if constexpr (!__is_same(AT, bf16)) {                                    \
      _Pragma("unroll") for (int i = 0; i < 2; ++i) {                        \
        int cch = tid + i * 256;                                             \
        int row = cch >> 2, kc = (cch & 3) * 8;                              \
        *(bf16x8*)&lA[buf][row][kc] =                                        \
            load8(&A[(long)(bm + row) * K + k0 + kc]);                       \
      }                                                                      \
    }                                                                        \
  }

  STAGE_DMA(0, 0);
  __syncthreads();

  for (int t = 0; t < NT; ++t) {
    const int buf = t & 1;
    if (t + 1 < NT) STAGE_DMA(buf ^ 1, t + 1);  // in flight during compute
    bf16x8 af[4], bfr[4];
#pragma unroll
    for (int i = 0; i < 4; ++i) {
      af[i]  = *(const bf16x8*)&lA[buf][wm + i * 16 + l16][quad * 8];
      bfr[i] = *(const bf16x8*)&lB[buf][wn + i * 16 + l16][quad * 8];
    }
#pragma unroll
    for (int mi = 0; mi < 4; ++mi)
#pragma unroll
      for (int ni = 0; ni < 4; ++ni)
        acc[mi][ni] = __builtin_amdgcn_mfma_f32_16x16x32_bf16(
            af[mi], bfr[ni], acc[mi][ni], 0, 0, 0);
    __syncthreads();  // drains next-step DMA; releases buf for overwrite
  }
#undef STAGE_DMA

  // epilogue: C/D layout col=lane&15, row=quad*4+reg (m89-verified)
#pragma unroll
  for (int mi = 0; mi < 4; ++mi)
#pragma unroll
    for (int ni = 0; ni < 4; ++ni) {
      int col = bn + wn + ni * 16 + l16;
      float bv = bias[col];
#pragma unroll
      for (int r = 0; r < 4; ++r) {
        int row = bm + wm + mi * 16 + quad * 4 + r;
        C[(long)row * N + col] = (OT)(acc[mi][ni][r] + bv);
      }
    }
}

// ---------------------------------------------------------------------------
// Final GEMM: 128x64 tiles (512 blocks). R3's 2-phase BK=32 double-buffered
// gld16 prefetch (measured best). R16 XCD swizzle kept.
// ---------------------------------------------------------------------------
__global__ __launch_bounds__(256) void gemm_bt_64(const bf16* __restrict__ A,
                                                  const bf16* __restrict__ Bt,
                                                  const float* __restrict__ bias,
                                                  float* __restrict__ C,
                                                  int M, int N, int K) {
  __shared__ bf16 lA[2][128][32];
  __shared__ bf16 lB[2][64][32];
  const int tid = threadIdx.x;
  const int lane = tid & 63, wave = tid >> 6;
  const int quad = lane >> 4, l16 = lane & 15;
  const int id = blockIdx.x + (blockIdx.y << 4);
  const int nid = (id & 7) * 64 + (id >> 3);
  const int bm = (nid >> 4) * 128, bn = (nid & 15) * 64;
  const int wm = (wave >> 1) * 64, wn = (wave & 1) * 32;

  f32x4 acc[4][2] = {};
  const int NT = K >> 5;

#define STAGE64(buf, t)                                                      \
  {                                                                          \
    const int k0 = (t) << 5;                                                 \
    _Pragma("unroll") for (int i = 0; i < 2; ++i) {                          \
      const int nbase = wave * 128 + i * 64;                                 \
      const int n = nbase + lane;                                            \
      const int row = n >> 2, kc = (n & 3) * 8;                              \
      gld16(&lA[buf][0][0] + (long)nbase * 8,                                \
            &A[(long)(bm + row) * K + k0 + kc]);                             \
    }                                                                        \
    {                                                                        \
      const int nbase = wave * 64;                                           \
      const int n = nbase + lane;                                            \
      const int row = n >> 2, kc = (n & 3) * 8;                              \
      gld16(&lB[buf][0][0] + (long)nbase * 8,                                \
            &Bt[(long)(bn + row) * K + k0 + kc]);                            \
    }                                                                        \
  }

  STAGE64(0, 0);
  __syncthreads();

  for (int t = 0; t < NT; ++t) {
    const int buf = t & 1;
    if (t + 1 < NT) STAGE64(buf ^ 1, t + 1);
    bf16x8 af[4], bfr[2];
#pragma unroll
    for (int i = 0; i < 4; ++i)
      af[i] = *(const bf16x8*)&lA[buf][wm + i * 16 + l16][quad * 8];
#pragma unroll
    for (int i = 0; i < 2; ++i)
      bfr[i] = *(const bf16x8*)&lB[buf][wn + i * 16 + l16][quad * 8];
#pragma unroll
    for (int mi = 0; mi < 4; ++mi)
#pragma unroll
      for (int ni = 0; ni < 2; ++ni)
        acc[mi][ni] = __builtin_amdgcn_mfma_f32_16x16x32_bf16(
            af[mi], bfr[ni], acc[mi][ni], 0, 0, 0);
    __syncthreads();
  }
#undef STAGE64

#pragma unroll
  for (int mi = 0; mi < 4; ++mi)
#pragma unroll
    for (int ni = 0; ni < 2; ++ni) {
      int col = bn + wn + ni * 16 + l16;
      float bv = bias[col];
#pragma unroll
      for (int r = 0; r < 4; ++r) {
        int row = bm + wm + mi * 16 + quad * 4 + r;
        C[(long)row * N + col] = acc[mi][ni][r] + bv;
      }
    }
}

// ---------------------------------------------------------------------------
// Flash attention v10 = v8 + lgkmcnt-only barriers, WITHOUT setprio.
// R10 theory: R8's v9 bundled two changes. The lgkmcnt-only barrier is
// mechanism-sound (keeps the distance-2 register prefetch in flight across
// barriers instead of __syncthreads' vmcnt(0) drain). setprio, however, is
// miscast here: the catalog A/B (m190/m191) shows it helps only when waves
// run INDEPENDENT phases; our 8 waves are lockstep on shared K/V staging
// barriers — the m190 regime where it measured negative. v10 keeps the
// barrier fix, drops setprio.
// ---------------------------------------------------------------------------
#define SCALE_LOG2E 0.1803368801111244f  // (1/8) * log2(e)

__device__ inline void attn_step5(bool diag, int qloc, int quad, int l16,
                                  const bf16 (*lKb)[64], const bf16 (*lVb)[64],
                                  bf16 (*lpw)[72], const bf16x8* aq,
                                  f32x4* o, float& l_s) {
  const int sw = l16 & 7;
  f32x4 s[4];
#pragma unroll
  for (int ni = 0; ni < 4; ++ni) {
    f32x4 a = {};
#pragma unroll
    for (int c = 0; c < 2; ++c) {
      bf16x8 kf = *(const bf16x8*)&lKb[ni * 16 + l16][((c * 4 + quad) ^ sw) * 8];
      a = __builtin_amdgcn_mfma_f32_16x16x32_bf16(kf, aq[c], a, 0, 0, 0);
    }
    s[ni] = a * SCALE_LOG2E;
  }
  if (diag) {
#pragma unroll
    for (int ni = 0; ni < 4; ++ni)
#pragma unroll
      for (int r = 0; r < 4; ++r)
        if (ni * 16 + quad * 4 + r > qloc) s[ni][r] = -1e9f;  // exp2 -> 0
  }
  float rs = 0.f;
#pragma unroll
  for (int ni = 0; ni < 4; ++ni) {
    bf16x4 p4;
#pragma unroll
    for (int r = 0; r < 4; ++r) {
      float p = exp2g(s[ni][r]);
      p4[r] = (bf16)p;
      rs += p;
    }
    *(bf16x4*)&lpw[l16][ni * 16 + quad * 4] = p4;  // P[q][key], packed b64
  }
  l_s += rs;
#pragma unroll
  for (int c = 0; c < 2; ++c) {
    bf16x8 ap = *(const bf16x8*)&lpw[l16][c * 32 + quad * 8];
#pragma unroll
    for (int di = 0; di < 4; ++di) {
      bf16x8 vf = *(const bf16x8*)&lVb[di * 16 + l16][((c * 4 + quad) ^ sw) * 8];
      o[di] = __builtin_amdgcn_mfma_f32_16x16x32_bf16(vf, ap, o[di], 0, 0, 0);
    }
  }
}

__device__ inline void store_o(bf16* Ob, int qrow, int lane, int quad, int l16,
                               bf16 (*lpw)[72], const f32x4* o, float l_s) {
  float rs = l_s;
  rs += __shfl_xor(rs, 16);
  rs += __shfl_xor(rs, 32);
  const float inv = 1.0f / rs;
#pragma unroll
  for (int di = 0; di < 4; ++di) {
    bf16x4 p4;
#pragma unroll
    for (int r = 0; r < 4; ++r) p4[r] = (bf16)(o[di][r] * inv);
    *(bf16x4*)&lpw[l16][di * 16 + quad * 4] = p4;
  }
  const int q = lane >> 2, db = (lane & 3) * 16;
  bf16x8 v0 = *(const bf16x8*)&lpw[q][db];
  bf16x8 v1 = *(const bf16x8*)&lpw[q][db + 8];
  *(bf16x8*)&Ob[(long)(qrow + q) * D_ + db] = v0;
  *(bf16x8*)&Ob[(long)(qrow + q) * D_ + db + 8] = v1;
}

__global__ __launch_bounds__(512) void flash_attn10(const bf16* __restrict__ Q,
                                                    const bf16* __restrict__ K,
                                                    const bf16* __restrict__ VT,
                                                    bf16* __restrict__ O) {
  __shared__ bf16 lK[2][64][64];   // [key][dim], chunk-col XOR-swizzled
  __shared__ bf16 lV[2][64][64];   // [dim][key], chunk-col XOR-swizzled
  __shared__ bf16 lp[8][16][72];   // per-wave P / O bounce
  const int tid = threadIdx.x;
  const int lane = tid & 63, wave = tid >> 6;  // 0..7
  const int quad = lane >> 4, l16 = lane & 15;
  const int x = blockIdx.x, bh = blockIdx.y;
  // adjacent pairing; reversed in the upper bh half for per-CU load balance
  const bool flip = (bh & 16) != 0;
  const int qtA = flip ? 30 - 2 * x : 2 * x;
  const int qtB = qtA + 1;
  const bool isB = wave >= 4;
  const int w4 = wave & 3;
  const int myqt = isB ? qtB : qtA;
  const int b = bh >> 4, h = bh & 15;
  const bf16* Qb = Q + (long)b * S_ * D_ + h * HD_;
  const bf16* Kb = K + (long)b * S_ * D_ + h * HD_;
  const bf16* Vb = VT + (long)bh * HD_ * S_;
  const int qrow = myqt * 64 + w4 * 16;
  const int qloc = w4 * 16 + l16;

  bf16x8 aq[2];
#pragma unroll
  for (int c = 0; c < 2; ++c)
    aq[c] = *(const bf16x8*)&Qb[(long)(qrow + l16) * D_ + c * 32 + quad * 8];

  f32x4 o[4] = {};
  float l_s = 0.f;

  const int srow = tid >> 3, scol = tid & 7;
  const int swcol = (scol ^ (srow & 7)) * 8;
  const int ktMax = qtB;  // always odd

  // prologue: stage tile 0 into buf0; issue tile 1 (in flight across barrier)
  bf16x8 rkA, rvA, rkB, rvB;
  rkA = *(const bf16x8*)&Kb[(long)srow * D_ + scol * 8];
  rvA = *(const bf16x8*)&Vb[(long)srow * S_ + scol * 8];
  *(bf16x8*)&lK[0][srow][swcol] = rkA;
  *(bf16x8*)&lV[0][srow][swcol] = rvA;
  rkA = *(const bf16x8*)&Kb[(long)(64 + srow) * D_ + scol * 8];
  rvA = *(const bf16x8*)&Vb[(long)srow * S_ + 64 + scol * 8];
  barrier_lds();  // publish LDS; keep tile-1 loads in flight

  for (int kt = 0; kt < ktMax; kt += 2) {
    // ---- even step: compute tile kt on buf0; commit rA (tile kt+1) -> buf1
    if (kt + 2 <= ktMax) {  // issue tile kt+2 -> rB (consumed next even step)
      const long k0 = (long)(kt + 2) * 64;
      rkB = *(const bf16x8*)&Kb[(k0 + srow) * D_ + scol * 8];
      rvB = *(const bf16x8*)&Vb[(long)srow * S_ + k0 + scol * 8];
    }
    if (isB || kt <= qtA)
      attn_step5(kt == myqt, qloc, quad, l16, lK[0], lV[0], lp[wave], aq,
                 o, l_s);
    *(bf16x8*)&lK[1][srow][swcol] = rkA;  // compiler waits vmcnt for rA only
    *(bf16x8*)&lV[1][srow][swcol] = rvA;
    barrier_lds();  // rB loads stay in flight across the barrier
    // ---- odd step: compute tile kt+1 on buf1; commit rB (tile kt+2) -> buf0
    if (kt + 3 <= ktMax) {  // issue tile kt+3 -> rA
      const long k0 = (long)(kt + 3) * 64;
      rkA = *(const bf16x8*)&Kb[(k0 + srow) * D_ + scol * 8];
      rvA = *(const bf16x8*)&Vb[(long)srow * S_ + k0 + scol * 8];
    }
    if (isB || kt + 1 <= qtA)
      attn_step5(kt + 1 == myqt, qloc, quad, l16, lK[1], lV[1], lp[wave], aq,
                 o, l_s);
    if (kt + 1 < ktMax) {
      *(bf16x8*)&lK[0][srow][swcol] = rkB;
      *(bf16x8*)&lV[0][srow][swcol] = rvB;
      barrier_lds();
    }
  }

  bf16* Ob = O + (long)b * S_ * D_ + h * HD_;
  store_o(Ob, qrow, lane, quad, l16, lp[wave], o, l_s);
}

// ---------------------------------------------------------------------------
extern "C" void kernel_launch(void* const* d_in, const int* in_sizes, int n_in,
                              void* d_out, int out_size, void* d_ws, size_t ws_size,
                              hipStream_t stream) {
  (void)in_sizes; (void)n_in; (void)out_size;
  const float* q_in = (const float*)d_in[0];
  const float* k_in = (const float*)d_in[1];
  const float* v_in = (const float*)d_in[2];
  const float* Wq   = (const float*)d_in[3];
  const float* bq   = (const float*)d_in[4];
  const float* Wk   = (const float*)d_in[5];
  const float* bk   = (const float*)d_in[6];
  const float* Wv   = (const float*)d_in[7];
  const float* bv   = (const float*)d_in[8];
  const float* Wo   = (const float*)d_in[9];
  const float* bo   = (const float*)d_in[10];
  float* out = (float*)d_out;  // reference output dtype is float32

  bf16* ws = (bf16*)d_ws;
  const size_t WSZ = (size_t)D_ * D_;       // 1M elements
  const size_t TSZ = (size_t)B_ * S_ * D_;  // 4M elements
  bf16* WqT = ws;
  bf16* WkT = WqT + WSZ;
  bf16* WvT = WkT + WSZ;
  bf16* WoT = WvT + WSZ;
  bf16* Qp  = WoT + WSZ;
  bf16* Kp  = Qp + TSZ;
  bf16* Vp  = Kp + TSZ;
  bf16* VTp = Vp + TSZ;
  bf16* Ap  = VTp + TSZ;   // 48 MB used through here (validated R2-R14)
  // converted inputs: lifetimes end before VTp/Ap are written -> overlap
  bf16* Xq  = VTp;
  bf16* Xk  = Ap;
  bf16* Xv  = Ap + TSZ;    // needs ws_size >= 56 MB (validated R8-R14)
  const bool pre = ws_size >= (4 * WSZ + 6 * TSZ) * sizeof(bf16);

  dim3 blk(256);
  transpose_w<<<dim3(32, 32, pre ? 16 : 4), blk, 0, stream>>>(
      Wq, Wk, Wv, Wo, WqT, WkT, WvT, WoT, q_in, k_in, v_in, Xq, Xk, Xv);

  if (pre)
    gemm_bt_dma<bf16, bf16><<<dim3(8, 32, 3), blk, 0, stream>>>(
        Xq, Xk, Xv, WqT, WkT, WvT, bq, bk, bv, Qp, Kp, Vp, MM, D_, D_);
  else
    gemm_bt_dma<float, bf16><<<dim3(8, 32, 3), blk, 0, stream>>>(
        q_in, k_in, v_in, WqT, WkT, WvT, bq, bk, bv, Qp, Kp, Vp, MM, D_, D_);

  transpose_v64<<<dim3(S_ / 64, B_ * H_), blk, 0, stream>>>(Vp, VTp);

  flash_attn10<<<dim3(16, B_ * H_), dim3(512), 0, stream>>>(Qp, Kp, VTp, Ap);

  gemm_bt_64<<<dim3(16, 32), blk, 0, stream>>>(Ap, WoT, bo, out, MM, D_, D_);
}